// Round 3
// baseline (1302.184 us; speedup 1.0000x reference)
//
#include <hip/hip_runtime.h>
#include <hip/hip_fp8.h>

#define TOK 4096
#define NPAT 65536
#define PDIM 512
#define DDIM 1024
#define CAP 1024
#define RSEL 256
#define WLO 112   // fp32-verify window: refined ranks [WLO, WLO+WIN)
#define WIN 32

typedef __attribute__((ext_vector_type(8))) short bf16x8;
typedef __attribute__((ext_vector_type(4))) float f32x4;
typedef unsigned short u16;
typedef unsigned int u32;
typedef unsigned long long u64;

__device__ __forceinline__ u16 f2b(float f) {
  union { float f; u32 u; } x; x.f = f;
  u32 r = x.u + 0x7FFFu + ((x.u >> 16) & 1u);   // RNE fp32->bf16
  return (u16)(r >> 16);
}
__device__ __forceinline__ float b2f(u32 h) {
  union { u32 u; float f; } x; x.u = h << 16; return x.f;
}
__device__ __forceinline__ u32 f2f8(float v) {   // OCP e4m3, RNE+sat via HW
  __hip_fp8_e4m3 t(v);
  return (u32)(unsigned char)t.__x;
}

__device__ __forceinline__ void gl2lds16(const void* g, void* l) {
  __builtin_amdgcn_global_load_lds((const __attribute__((address_space(1))) u32*)g,
                                   (__attribute__((address_space(3))) u32*)l, 16, 0, 0);
}

__device__ __forceinline__ u32 fkey(float f) {  // monotonic float->uint
  u32 u = __float_as_uint(f);
  u ^= (u >> 31) ? 0xFFFFFFFFu : 0x80000000u;
  return u;
}

// bitonic sort of 256 u64 keys in LDS, 256 threads, ascending
__device__ __forceinline__ void sort256(u64* ks, int tid) {
  for (int k = 2; k <= 256; k <<= 1) {
    for (int j = k >> 1; j > 0; j >>= 1) {
      int ixj = tid ^ j;
      if (ixj > tid) {
        u64 a = ks[tid], b = ks[ixj];
        if ((a > b) == ((tid & k) == 0)) { ks[tid] = b; ks[ixj] = a; }
      }
      __syncthreads();
    }
  }
}

// ---- pattern norms + normalized fp8 (scale 32) + normalized bf16 copies ------
__global__ __launch_bounds__(256) void k_patnorm(const float* __restrict__ pat,
                                                 unsigned char* __restrict__ pnf8,
                                                 u16* __restrict__ pnb,
                                                 float* __restrict__ prn,
                                                 float* __restrict__ pnorm_) {
  int row = blockIdx.x * 4 + (threadIdx.x >> 6);
  int lane = threadIdx.x & 63;
  const float* p = pat + (size_t)row * PDIM + lane * 8;
  float4 v0 = *(const float4*)p;
  float4 v1 = *(const float4*)(p + 4);
  float s = v0.x*v0.x + v0.y*v0.y + v0.z*v0.z + v0.w*v0.w
          + v1.x*v1.x + v1.y*v1.y + v1.z*v1.z + v1.w*v1.w;
  #pragma unroll
  for (int m = 1; m < 64; m <<= 1) s += __shfl_xor(s, m);
  float nrm = fmaxf(sqrtf(s), 1e-8f);
  float rn = 1.0f / nrm;
  if (lane == 0) { prn[row] = rn; pnorm_[row] = nrm; }
  float sc = rn * 32.0f;
  uint2 o;
  o.x = f2f8(v0.x*sc) | (f2f8(v0.y*sc) << 8) | (f2f8(v0.z*sc) << 16) | (f2f8(v0.w*sc) << 24);
  o.y = f2f8(v1.x*sc) | (f2f8(v1.y*sc) << 8) | (f2f8(v1.z*sc) << 16) | (f2f8(v1.w*sc) << 24);
  *(uint2*)(pnf8 + (size_t)row * PDIM + lane * 8) = o;
  uint4 ob;
  ob.x = (u32)f2b(v0.x*rn) | ((u32)f2b(v0.y*rn) << 16);
  ob.y = (u32)f2b(v0.z*rn) | ((u32)f2b(v0.w*rn) << 16);
  ob.z = (u32)f2b(v1.x*rn) | ((u32)f2b(v1.y*rn) << 16);
  ob.w = (u32)f2b(v1.z*rn) | ((u32)f2b(v1.w*rn) << 16);
  *(uint4*)(pnb + (size_t)row * PDIM + lane * 8) = ob;
}

__global__ __launch_bounds__(256) void k_zero(int* __restrict__ p, int n) {
  int i = blockIdx.x * 256 + threadIdx.x;
  if (i < n) p[i] = 0;
}

__global__ __launch_bounds__(256) void k_tobf16(const float* __restrict__ s,
                                                u16* __restrict__ d, int n) {
  int i = blockIdx.x * 256 + threadIdx.x;
  if (i < n) d[i] = f2b(s[i]);
}

// ---- split fp32 -> bf16 hi/lo (float4 per thread) ----------------------------
__global__ __launch_bounds__(256) void k_split4(const float* __restrict__ s,
                                                u16* __restrict__ hi,
                                                u16* __restrict__ lo, int n4) {
  int i = blockIdx.x * 256 + threadIdx.x;
  if (i >= n4) return;
  float4 v = *(const float4*)(s + (size_t)i * 4);
  ushort4 h, l;
  h.x = f2b(v.x); l.x = f2b(v.x - b2f(h.x));
  h.y = f2b(v.y); l.y = f2b(v.y - b2f(h.y));
  h.z = f2b(v.z); l.z = f2b(v.z - b2f(h.z));
  h.w = f2b(v.w); l.w = f2b(v.w - b2f(h.w));
  *(ushort4*)(hi + (size_t)i * 4) = h;
  *(ushort4*)(lo + (size_t)i * 4) = l;
}

// ---- encoder via split-bf16 MFMA: enc = xh(wh+wl)^T + xl wh^T + eb -----------
__global__ __launch_bounds__(256) void k_enc3(const u16* __restrict__ xh,
                                              const u16* __restrict__ xl,
                                              const u16* __restrict__ wh,
                                              const u16* __restrict__ wl,
                                              const float* __restrict__ eb,
                                              float* __restrict__ enc) {
  __shared__ __align__(16) u16 As[64 * 32];
  __shared__ __align__(16) u16 Bs[128 * 32];
  const int bm = blockIdx.x, bn = blockIdx.y;
  const int tid = threadIdx.x, lane = tid & 63, w = tid >> 6;
  const int wm = w >> 1, wn = w & 1;
  f32x4 acc[2][4];
  #pragma unroll
  for (int i = 0; i < 2; ++i)
    #pragma unroll
    for (int j = 0; j < 4; ++j) acc[i][j] = (f32x4){0.f, 0.f, 0.f, 0.f};

  const int arow = tid >> 2, ael = (tid & 3) * 8;
  const int fm = (lane & 15) * 32 + (lane >> 4) * 8;
  const u16* APh[3] = {xh, xh, xl};
  const u16* BPh[3] = {wh, wl, wh};

  for (int ph = 0; ph < 3; ++ph) {
    const u16* Ag = APh[ph] + (size_t)(bm * 64 + arow) * DDIM + ael;
    const u16* Bg0 = BPh[ph] + (size_t)(bn * 128 + arow) * DDIM + ael;
    const u16* Bg1 = BPh[ph] + (size_t)(bn * 128 + 64 + arow) * DDIM + ael;
    for (int kt = 0; kt < 32; ++kt) {
      gl2lds16(Ag + kt * 32, As + (size_t)tid * 8);
      gl2lds16(Bg0 + kt * 32, Bs + (size_t)tid * 8);
      gl2lds16(Bg1 + kt * 32, Bs + (size_t)(tid + 256) * 8);
      __syncthreads();
      bf16x8 af[2], bf[4];
      #pragma unroll
      for (int i = 0; i < 2; ++i) af[i] = *(const bf16x8*)&As[(wm * 32 + i * 16) * 32 + fm];
      #pragma unroll
      for (int j = 0; j < 4; ++j) bf[j] = *(const bf16x8*)&Bs[(wn * 64 + j * 16) * 32 + fm];
      #pragma unroll
      for (int i = 0; i < 2; ++i)
        #pragma unroll
        for (int j = 0; j < 4; ++j)
          acc[i][j] = __builtin_amdgcn_mfma_f32_16x16x32_bf16(af[i], bf[j], acc[i][j], 0, 0, 0);
      __syncthreads();
    }
  }
  #pragma unroll
  for (int i = 0; i < 2; ++i) {
    int rbase = bm * 64 + wm * 32 + i * 16 + ((lane >> 4) << 2);
    #pragma unroll
    for (int j = 0; j < 4; ++j) {
      int col = bn * 128 + wn * 64 + j * 16 + (lane & 15);
      float bias = eb[col];
      #pragma unroll
      for (int r = 0; r < 4; ++r)
        enc[(size_t)(rbase + r) * PDIM + col] = acc[i][j][r] + bias;
    }
  }
}

// ---- normalize enc rows: fp32 copy + fp8 copy (scale 32) ---------------------
__global__ __launch_bounds__(256) void k_encnorm(const float* __restrict__ enc,
                                                 float* __restrict__ encn,
                                                 unsigned char* __restrict__ encf8) {
  int row = blockIdx.x * 4 + (threadIdx.x >> 6);
  int lane = threadIdx.x & 63;
  const float* p = enc + (size_t)row * PDIM + lane * 8;
  float4 v0 = *(const float4*)p;
  float4 v1 = *(const float4*)(p + 4);
  float s = v0.x*v0.x + v0.y*v0.y + v0.z*v0.z + v0.w*v0.w
          + v1.x*v1.x + v1.y*v1.y + v1.z*v1.z + v1.w*v1.w;
  #pragma unroll
  for (int m = 1; m < 64; m <<= 1) s += __shfl_xor(s, m);
  float rn = 1.0f / fmaxf(sqrtf(s), 1e-8f);
  float4 n0 = {v0.x*rn, v0.y*rn, v0.z*rn, v0.w*rn};
  float4 n1 = {v1.x*rn, v1.y*rn, v1.z*rn, v1.w*rn};
  float* q = encn + (size_t)row * PDIM + lane * 8;
  *(float4*)q = n0;
  *(float4*)(q + 4) = n1;
  uint2 o;
  o.x = f2f8(n0.x*32.f) | (f2f8(n0.y*32.f) << 8) | (f2f8(n0.z*32.f) << 16) | (f2f8(n0.w*32.f) << 24);
  o.y = f2f8(n1.x*32.f) | (f2f8(n1.y*32.f) << 8) | (f2f8(n1.z*32.f) << 16) | (f2f8(n1.w*32.f) << 24);
  *(uint2*)(encf8 + (size_t)row * PDIM + lane * 8) = o;
}

// ---- coarse sim: fp8 MFMA, A-resident-in-LDS, barrier-free, depth-4 prefetch -
// 1-D grid of 512; XCD-aware remap so each XCD sees only 2 bn-slices (4MB L2 fit)
__global__ __launch_bounds__(512, 4) void k_sim(const unsigned char* __restrict__ A,
                                                const unsigned char* __restrict__ B,
                                                int* __restrict__ cnt,
                                                float* __restrict__ cval,
                                                int* __restrict__ cidx) {
  __shared__ __align__(16) unsigned char As[65536];  // [16 kt][128 row][32 B]
  const int l = blockIdx.x;
  const int bn = 2 * (l & 7) + (l >> 8);   // XCD = l%8 -> bn in {2x, 2x+1}
  const int bm = (l >> 3) & 31;
  const int nb0 = bn * 4096;
  const int tid = threadIdx.x, lane = tid & 63, w = tid >> 6;

  // stage A-tile once: 64 KB
  {
    int row = (tid >> 1) & 127;
    int kt0 = tid >> 8;
    int c = (tid & 1) * 16;
    const unsigned char* g = A + (size_t)(bm * 128 + row) * PDIM + kt0 * 32 + c;
    #pragma unroll
    for (int s = 0; s < 8; ++s)
      gl2lds16(g + s * 64, &As[s * 8192 + tid * 16]);
  }

  f32x4 acc[8][2];
  #pragma unroll
  for (int m = 0; m < 8; ++m) {
    acc[m][0] = (f32x4){0.f, 0.f, 0.f, 0.f};
    acc[m][1] = (f32x4){0.f, 0.f, 0.f, 0.f};
  }
  const int baseA = (lane & 15) * 32 + (lane >> 4) * 8;
  const unsigned char* bp0 = B + (size_t)(nb0 + w * 32 + (lane & 15)) * PDIM + (lane >> 4) * 8;
  const unsigned char* bp1 = bp0 + 16 * PDIM;

  __syncthreads();   // A-tile ready; no barriers after this point

  long rq0[4], rq1[4];
  #pragma unroll
  for (int u = 0; u < 4; ++u) {       // prologue: it=0..3 (kt<15 -> delta 32)
    rq0[u] = *(const long*)bp0;
    rq1[u] = *(const long*)bp1;
    bp0 += 32; bp1 += 32;
  }
  const float THRS = 112.64f;   // 0.11 * 32 * 32

  for (int it = 0; it < 256; ++it) {
    const int kt = it & 15;
    const int slot = it & 3;
    long bc0 = rq0[slot], bc1 = rq1[slot];
    int ip = it + 4;
    if (ip < 256) {
      rq0[slot] = *(const long*)bp0;
      rq1[slot] = *(const long*)bp1;
      long d = ((ip & 15) == 15) ? (long)(256 * PDIM - 15 * 32) : 32;
      bp0 += d; bp1 += d;
    }
    long a[8];
    #pragma unroll
    for (int m = 0; m < 8; ++m)
      a[m] = *(const long*)&As[kt * 4096 + m * 512 + baseA];
    #pragma unroll
    for (int m = 0; m < 8; ++m) {
      acc[m][0] = __builtin_amdgcn_mfma_f32_16x16x32_fp8_fp8(a[m], bc0, acc[m][0], 0, 0, 0);
      acc[m][1] = __builtin_amdgcn_mfma_f32_16x16x32_fp8_fp8(a[m], bc1, acc[m][1], 0, 0, 0);
    }
    if (kt == 15) {   // end of pass: threshold-push epilogue, reset acc
      int ncol = nb0 + (it >> 4) * 256 + w * 32;
      #pragma unroll
      for (int m = 0; m < 8; ++m) {
        int tokbase = bm * 128 + m * 16 + ((lane >> 4) << 2);
        #pragma unroll
        for (int j = 0; j < 2; ++j) {
          int pc = ncol + j * 16 + (lane & 15);
          #pragma unroll
          for (int r = 0; r < 4; ++r) {
            float v = acc[m][j][r];
            if (v > THRS) {
              int tt = tokbase + r;
              int pos = atomicAdd(&cnt[tt], 1);
              if (pos < CAP) {
                cval[(size_t)tt * CAP + pos] = v;
                cidx[(size_t)tt * CAP + pos] = pc;
              }
            }
            acc[m][j][r] = 0.f;
          }
        }
      }
    }
  }
}

// ---- per-token: coarse sort -> bf16 rerank 256 -> fp32 verify window ->
//      exact top-128 -> bf16 winner-sum
__global__ __launch_bounds__(256) void k_select(const float* __restrict__ pat,
                                                const float* __restrict__ prn,
                                                const float* __restrict__ pnorm_,
                                                const u16* __restrict__ pnb,
                                                const float* __restrict__ encn,
                                                const int* __restrict__ cnt,
                                                const float* __restrict__ cval,
                                                const int* __restrict__ cidx,
                                                u16* __restrict__ meanb) {
  __shared__ u64 keys[CAP];
  __shared__ int fidx[RSEL];
  __shared__ u64 keys2[RSEL];
  __shared__ float wsum[4][PDIM];
  const int t = blockIdx.x;
  const int tid = threadIdx.x;
  const int lane = tid & 63;
  const int w = tid >> 6;
  const int n = min(cnt[t], CAP);

  // 1. coarse candidates -> sort desc(val), asc(idx)
  for (int i = tid; i < CAP; i += 256) {
    u64 key = ~0ull;
    if (i < n) {
      u32 uk = fkey(cval[(size_t)t * CAP + i]);
      key = ((u64)(~uk) << 32) | (u32)cidx[(size_t)t * CAP + i];
    }
    keys[i] = key;
  }
  __syncthreads();
  for (int k = 2; k <= CAP; k <<= 1) {
    for (int j = k >> 1; j > 0; j >>= 1) {
      for (int i = tid; i < CAP; i += 256) {
        int ixj = i ^ j;
        if (ixj > i) {
          u64 a = keys[i], b = keys[ixj];
          if ((a > b) == ((i & k) == 0)) { keys[i] = b; keys[ixj] = a; }
        }
      }
      __syncthreads();
    }
  }
  if (tid < RSEL) fidx[tid] = (int)(u32)(keys[tid] & 0xFFFFFFFFull);
  __syncthreads();

  const float* er = encn + (size_t)t * PDIM + lane * 8;
  float4 e0 = *(const float4*)er;
  float4 e1 = *(const float4*)(er + 4);

  // 2. bf16 rerank of coarse top-256 (normalized bf16 rows; noise ~1e-4)
  for (int c0 = w * 64; c0 < w * 64 + 64; c0 += 4) {
    int id[4]; bool ok[4]; uint4 q[4];
    #pragma unroll
    for (int u = 0; u < 4; ++u) {
      int iv = fidx[c0 + u];
      ok[u] = ((u32)iv < (u32)NPAT);
      id[u] = ok[u] ? iv : 0;
      q[u] = *(const uint4*)(pnb + (size_t)id[u] * PDIM + lane * 8);
    }
    #pragma unroll
    for (int u = 0; u < 4; ++u) {
      float dd = b2f(q[u].x & 0xffff)*e0.x + b2f(q[u].x >> 16)*e0.y
               + b2f(q[u].y & 0xffff)*e0.z + b2f(q[u].y >> 16)*e0.w
               + b2f(q[u].z & 0xffff)*e1.x + b2f(q[u].z >> 16)*e1.y
               + b2f(q[u].w & 0xffff)*e1.z + b2f(q[u].w >> 16)*e1.w;
      #pragma unroll
      for (int m = 1; m < 64; m <<= 1) dd += __shfl_xor(dd, m);
      if (lane == 0)
        keys2[c0 + u] = ok[u] ? (((u64)(~fkey(dd)) << 32) | (u32)id[u]) : ~0ull;
    }
  }
  __syncthreads();
  sort256(keys2, tid);

  // 3. fp32 verify of refined ranks [WLO, WLO+WIN): exact sim = dot(encn,pat)*prn
  for (int b = 0; b < 2; ++b) {
    int c0 = WLO + w * 8 + b * 4;
    int id[4]; bool ok[4]; float4 p0[4], p1[4];
    #pragma unroll
    for (int u = 0; u < 4; ++u) {
      int iv = (int)(u32)(keys2[c0 + u] & 0xFFFFFFFFull);
      ok[u] = ((u32)iv < (u32)NPAT);
      id[u] = ok[u] ? iv : 0;
      const float* pr = pat + (size_t)id[u] * PDIM + lane * 8;
      p0[u] = *(const float4*)pr;
      p1[u] = *(const float4*)(pr + 4);
    }
    #pragma unroll
    for (int u = 0; u < 4; ++u) {
      float dd = p0[u].x*e0.x + p0[u].y*e0.y + p0[u].z*e0.z + p0[u].w*e0.w
               + p1[u].x*e1.x + p1[u].y*e1.y + p1[u].z*e1.z + p1[u].w*e1.w;
      #pragma unroll
      for (int m = 1; m < 64; m <<= 1) dd += __shfl_xor(dd, m);
      if (lane == 0) {
        float val = dd * prn[id[u]];
        keys2[c0 + u] = ok[u] ? (((u64)(~fkey(val)) << 32) | (u32)id[u]) : ~0ull;
      }
    }
  }
  __syncthreads();
  sort256(keys2, tid);

  // 4. winner-sum: top-128, bf16 normalized rows x stored norm
  float4 s0 = {0,0,0,0}, s1 = {0,0,0,0};
  for (int c0 = w * 32; c0 < w * 32 + 32; c0 += 4) {
    int id[4]; float nm[4]; uint4 q[4];
    #pragma unroll
    for (int u = 0; u < 4; ++u) {
      int iv = (int)(u32)(keys2[c0 + u] & 0xFFFFFFFFull);
      bool ok = ((u32)iv < (u32)NPAT);
      id[u] = ok ? iv : 0;
      q[u] = *(const uint4*)(pnb + (size_t)id[u] * PDIM + lane * 8);
      nm[u] = ok ? pnorm_[id[u]] : 0.0f;
    }
    #pragma unroll
    for (int u = 0; u < 4; ++u) {
      s0.x += b2f(q[u].x & 0xffff) * nm[u]; s0.y += b2f(q[u].x >> 16) * nm[u];
      s0.z += b2f(q[u].y & 0xffff) * nm[u]; s0.w += b2f(q[u].y >> 16) * nm[u];
      s1.x += b2f(q[u].z & 0xffff) * nm[u]; s1.y += b2f(q[u].z >> 16) * nm[u];
      s1.z += b2f(q[u].w & 0xffff) * nm[u]; s1.w += b2f(q[u].w >> 16) * nm[u];
    }
  }
  *(float4*)&wsum[w][lane * 8]     = s0;
  *(float4*)&wsum[w][lane * 8 + 4] = s1;
  __syncthreads();
  for (int dd = tid; dd < PDIM; dd += 256) {
    float m = (wsum[0][dd] + wsum[1][dd] + wsum[2][dd] + wsum[3][dd]) * (1.0f / 128.0f);
    meanb[(size_t)t * PDIM + dd] = f2b(m);
  }
}

// ---- decoder (bf16 MFMA): out = x + alpha*(mean @ dec_w^T + dec_b) -----------
__global__ __launch_bounds__(256) void k_dec(const u16* __restrict__ A,
                                             const u16* __restrict__ B,
                                             const float* __restrict__ x,
                                             const float* __restrict__ alpha,
                                             const float* __restrict__ db,
                                             float* __restrict__ out) {
  __shared__ __align__(16) u16 As[128 * 32];
  __shared__ __align__(16) u16 Bs[128 * 32];
  const int bm = blockIdx.x, bn = blockIdx.y;
  const int tid = threadIdx.x, lane = tid & 63, w = tid >> 6;
  const int wm = w >> 1, wn = w & 1;
  f32x4 acc[4][4];
  #pragma unroll
  for (int i = 0; i < 4; ++i)
    #pragma unroll
    for (int j = 0; j < 4; ++j) acc[i][j] = (f32x4){0.f, 0.f, 0.f, 0.f};

  const int c0 = w * 2, c1 = w * 2 + 1;
  const int lrow = lane >> 2, lk = (lane & 3) * 8;
  const u16* gA0 = A + (size_t)(bm * 128 + c0 * 16 + lrow) * PDIM + lk;
  const u16* gA1 = A + (size_t)(bm * 128 + c1 * 16 + lrow) * PDIM + lk;
  const u16* gB0 = B + (size_t)(bn * 128 + c0 * 16 + lrow) * PDIM + lk;
  const u16* gB1 = B + (size_t)(bn * 128 + c1 * 16 + lrow) * PDIM + lk;
  u16* lA0 = &As[c0 * 512]; u16* lA1 = &As[c1 * 512];
  u16* lB0 = &Bs[c0 * 512]; u16* lB1 = &Bs[c1 * 512];
  const int fm = (lane & 15) * 32 + (lane >> 4) * 8;

  for (int kt = 0; kt < 16; ++kt) {
    gl2lds16(gA0 + kt * 32, lA0);
    gl2lds16(gA1 + kt * 32, lA1);
    gl2lds16(gB0 + kt * 32, lB0);
    gl2lds16(gB1 + kt * 32, lB1);
    __syncthreads();
    bf16x8 af[4], bf[4];
    #pragma unroll
    for (int i = 0; i < 4; ++i) {
      af[i] = *(const bf16x8*)&As[(wm * 64 + i * 16) * 32 + fm];
      bf[i] = *(const bf16x8*)&Bs[(wn * 64 + i * 16) * 32 + fm];
    }
    #pragma unroll
    for (int i = 0; i < 4; ++i)
      #pragma unroll
      for (int j = 0; j < 4; ++j)
        acc[i][j] = __builtin_amdgcn_mfma_f32_16x16x32_bf16(af[i], bf[j], acc[i][j], 0, 0, 0);
    __syncthreads();
  }

  const float al = alpha[0];
  #pragma unroll
  for (int i = 0; i < 4; ++i) {
    int tbase = bm * 128 + wm * 64 + i * 16 + ((lane >> 4) << 2);
    #pragma unroll
    for (int j = 0; j < 4; ++j) {
      int dcol = bn * 128 + wn * 64 + j * 16 + (lane & 15);
      float bias = db[dcol];
      #pragma unroll
      for (int r = 0; r < 4; ++r) {
        int tt = tbase + r;
        size_t oi = (size_t)tt * DDIM + dcol;
        out[oi] = x[oi] + al * (acc[i][j][r] + bias);
      }
    }
  }
}

extern "C" void kernel_launch(void* const* d_in, const int* in_sizes, int n_in,
                              void* d_out, int out_size, void* d_ws, size_t ws_size,
                              hipStream_t stream) {
  const float* x     = (const float*)d_in[0];
  const float* pat   = (const float*)d_in[1];
  const float* alpha = (const float*)d_in[2];
  const float* enc_w = (const float*)d_in[3];
  const float* enc_b = (const float*)d_in[4];
  const float* dec_w = (const float*)d_in[5];
  const float* dec_b = (const float*)d_in[6];
  float* out = (float*)d_out;

  char* wsb = (char*)d_ws;
  size_t o = 0;
  auto alloc = [&](size_t bytes) -> void* {
    void* p = wsb + o;
    o += (bytes + 255) & ~(size_t)255;
    return p;
  };
  unsigned char* pnf8  = (unsigned char*)alloc((size_t)NPAT * PDIM);      // 32 MB
  u16*   pnb    = (u16*)  alloc((size_t)NPAT * PDIM * 2);                 // 64 MB
  float* prn    = (float*)alloc((size_t)NPAT * 4);                        // 256 KB
  float* pnorm_ = (float*)alloc((size_t)NPAT * 4);                        // 256 KB
  u16*   xh     = (u16*)  alloc((size_t)TOK * DDIM * 2);                  // 8 MB
  u16*   xl     = (u16*)  alloc((size_t)TOK * DDIM * 2);                  // 8 MB
  u16*   wh     = (u16*)  alloc((size_t)PDIM * DDIM * 2);                 // 1 MB
  u16*   wl     = (u16*)  alloc((size_t)PDIM * DDIM * 2);                 // 1 MB
  float* enc    = (float*)alloc((size_t)TOK * PDIM * 4);                  // 8 MB
  float* encn   = (float*)alloc((size_t)TOK * PDIM * 4);                  // 8 MB
  unsigned char* encf8 = (unsigned char*)alloc((size_t)TOK * PDIM);       // 2 MB
  int*   ccnt   = (int*)  alloc((size_t)TOK * 4);                         // 16 KB
  float* cvals  = (float*)alloc((size_t)TOK * CAP * 4);                   // 16 MB
  int*   cids   = (int*)  alloc((size_t)TOK * CAP * 4);                   // 16 MB
  u16*   meanb  = (u16*)  alloc((size_t)TOK * PDIM * 2);                  // 4 MB
  u16*   decwb  = (u16*)  alloc((size_t)DDIM * PDIM * 2);                 // 1 MB
  (void)ws_size; (void)in_sizes; (void)n_in; (void)out_size;

  k_patnorm<<<dim3(NPAT / 4), dim3(256), 0, stream>>>(pat, pnf8, pnb, prn, pnorm_);
  k_zero<<<dim3(TOK / 256), dim3(256), 0, stream>>>(ccnt, TOK);
  k_tobf16<<<dim3((DDIM * PDIM) / 256), dim3(256), 0, stream>>>(dec_w, decwb, DDIM * PDIM);
  k_split4<<<dim3((TOK * DDIM / 4) / 256), dim3(256), 0, stream>>>(x, xh, xl, TOK * DDIM / 4);
  k_split4<<<dim3((PDIM * DDIM / 4) / 256), dim3(256), 0, stream>>>(enc_w, wh, wl, PDIM * DDIM / 4);
  k_enc3<<<dim3(TOK / 64, PDIM / 128), dim3(256), 0, stream>>>(xh, xl, wh, wl, enc_b, enc);
  k_encnorm<<<dim3(TOK / 4), dim3(256), 0, stream>>>(enc, encn, encf8);
  k_sim<<<dim3(512), dim3(512), 0, stream>>>(encf8, pnf8, ccnt, cvals, cids);
  k_select<<<dim3(TOK), dim3(256), 0, stream>>>(pat, prn, pnorm_, pnb, encn, ccnt, cvals, cids, meanb);
  k_dec<<<dim3(TOK / 128, DDIM / 128), dim3(256), 0, stream>>>(meanb, decwb, x, alpha, dec_b, out);
}

// Round 4
// 1220.705 us; speedup vs baseline: 1.0667x; 1.0667x over previous
//
#include <hip/hip_runtime.h>
#include <hip/hip_fp8.h>

#define TOK 4096
#define NPAT 65536
#define PDIM 512
#define DDIM 1024
#define CAP 1024
#define RSEL 256
#define WLO 112   // fp32-verify window: refined ranks [WLO, WLO+WIN)
#define WIN 32

typedef __attribute__((ext_vector_type(8))) short bf16x8;
typedef __attribute__((ext_vector_type(4))) float f32x4;
typedef unsigned short u16;
typedef unsigned int u32;
typedef unsigned long long u64;

__device__ __forceinline__ u16 f2b(float f) {
  union { float f; u32 u; } x; x.f = f;
  u32 r = x.u + 0x7FFFu + ((x.u >> 16) & 1u);   // RNE fp32->bf16
  return (u16)(r >> 16);
}
__device__ __forceinline__ float b2f(u32 h) {
  union { u32 u; float f; } x; x.u = h << 16; return x.f;
}
__device__ __forceinline__ u32 f2f8(float v) {   // OCP e4m3, RNE+sat via HW
  __hip_fp8_e4m3 t(v);
  return (u32)(unsigned char)t.__x;
}

__device__ __forceinline__ void gl2lds16(const void* g, void* l) {
  __builtin_amdgcn_global_load_lds((const __attribute__((address_space(1))) u32*)g,
                                   (__attribute__((address_space(3))) u32*)l, 16, 0, 0);
}

__device__ __forceinline__ u32 fkey(float f) {  // monotonic float->uint
  u32 u = __float_as_uint(f);
  u ^= (u >> 31) ? 0xFFFFFFFFu : 0x80000000u;
  return u;
}

// ---- pattern norms + normalized fp8 (scale 32) + normalized bf16 copies ------
__global__ __launch_bounds__(256) void k_patnorm(const float* __restrict__ pat,
                                                 unsigned char* __restrict__ pnf8,
                                                 u16* __restrict__ pnb,
                                                 float* __restrict__ prn,
                                                 float* __restrict__ pnorm_) {
  int row = blockIdx.x * 4 + (threadIdx.x >> 6);
  int lane = threadIdx.x & 63;
  const float* p = pat + (size_t)row * PDIM + lane * 8;
  float4 v0 = *(const float4*)p;
  float4 v1 = *(const float4*)(p + 4);
  float s = v0.x*v0.x + v0.y*v0.y + v0.z*v0.z + v0.w*v0.w
          + v1.x*v1.x + v1.y*v1.y + v1.z*v1.z + v1.w*v1.w;
  #pragma unroll
  for (int m = 1; m < 64; m <<= 1) s += __shfl_xor(s, m);
  float nrm = fmaxf(sqrtf(s), 1e-8f);
  float rn = 1.0f / nrm;
  if (lane == 0) { prn[row] = rn; pnorm_[row] = nrm; }
  float sc = rn * 32.0f;
  uint2 o;
  o.x = f2f8(v0.x*sc) | (f2f8(v0.y*sc) << 8) | (f2f8(v0.z*sc) << 16) | (f2f8(v0.w*sc) << 24);
  o.y = f2f8(v1.x*sc) | (f2f8(v1.y*sc) << 8) | (f2f8(v1.z*sc) << 16) | (f2f8(v1.w*sc) << 24);
  *(uint2*)(pnf8 + (size_t)row * PDIM + lane * 8) = o;
  uint4 ob;
  ob.x = (u32)f2b(v0.x*rn) | ((u32)f2b(v0.y*rn) << 16);
  ob.y = (u32)f2b(v0.z*rn) | ((u32)f2b(v0.w*rn) << 16);
  ob.z = (u32)f2b(v1.x*rn) | ((u32)f2b(v1.y*rn) << 16);
  ob.w = (u32)f2b(v1.z*rn) | ((u32)f2b(v1.w*rn) << 16);
  *(uint4*)(pnb + (size_t)row * PDIM + lane * 8) = ob;
}

__global__ __launch_bounds__(256) void k_zero(int* __restrict__ p, int n) {
  int i = blockIdx.x * 256 + threadIdx.x;
  if (i < n) p[i] = 0;
}

__global__ __launch_bounds__(256) void k_tobf16(const float* __restrict__ s,
                                                u16* __restrict__ d, int n) {
  int i = blockIdx.x * 256 + threadIdx.x;
  if (i < n) d[i] = f2b(s[i]);
}

// ---- split fp32 -> bf16 hi/lo (float4 per thread) ----------------------------
__global__ __launch_bounds__(256) void k_split4(const float* __restrict__ s,
                                                u16* __restrict__ hi,
                                                u16* __restrict__ lo, int n4) {
  int i = blockIdx.x * 256 + threadIdx.x;
  if (i >= n4) return;
  float4 v = *(const float4*)(s + (size_t)i * 4);
  ushort4 h, l;
  h.x = f2b(v.x); l.x = f2b(v.x - b2f((u32)h.x));
  h.y = f2b(v.y); l.y = f2b(v.y - b2f((u32)h.y));
  h.z = f2b(v.z); l.z = f2b(v.z - b2f((u32)h.z));
  h.w = f2b(v.w); l.w = f2b(v.w - b2f((u32)h.w));
  *(ushort4*)(hi + (size_t)i * 4) = h;
  *(ushort4*)(lo + (size_t)i * 4) = l;
}

// ---- encoder via split-bf16 MFMA: enc = xh(wh+wl)^T + xl wh^T + eb -----------
__global__ __launch_bounds__(256) void k_enc3(const u16* __restrict__ xh,
                                              const u16* __restrict__ xl,
                                              const u16* __restrict__ wh,
                                              const u16* __restrict__ wl,
                                              const float* __restrict__ eb,
                                              float* __restrict__ enc) {
  __shared__ __align__(16) u16 As[64 * 32];
  __shared__ __align__(16) u16 Bs[128 * 32];
  const int bm = blockIdx.x, bn = blockIdx.y;
  const int tid = threadIdx.x, lane = tid & 63, w = tid >> 6;
  const int wm = w >> 1, wn = w & 1;
  f32x4 acc[2][4];
  #pragma unroll
  for (int i = 0; i < 2; ++i)
    #pragma unroll
    for (int j = 0; j < 4; ++j) acc[i][j] = (f32x4){0.f, 0.f, 0.f, 0.f};

  const int arow = tid >> 2, ael = (tid & 3) * 8;
  const int fm = (lane & 15) * 32 + (lane >> 4) * 8;
  const u16* APh[3] = {xh, xh, xl};
  const u16* BPh[3] = {wh, wl, wh};

  for (int ph = 0; ph < 3; ++ph) {
    const u16* Ag = APh[ph] + (size_t)(bm * 64 + arow) * DDIM + ael;
    const u16* Bg0 = BPh[ph] + (size_t)(bn * 128 + arow) * DDIM + ael;
    const u16* Bg1 = BPh[ph] + (size_t)(bn * 128 + 64 + arow) * DDIM + ael;
    for (int kt = 0; kt < 32; ++kt) {
      gl2lds16(Ag + kt * 32, As + (size_t)tid * 8);
      gl2lds16(Bg0 + kt * 32, Bs + (size_t)tid * 8);
      gl2lds16(Bg1 + kt * 32, Bs + (size_t)(tid + 256) * 8);
      __syncthreads();
      bf16x8 af[2], bf[4];
      #pragma unroll
      for (int i = 0; i < 2; ++i) af[i] = *(const bf16x8*)&As[(wm * 32 + i * 16) * 32 + fm];
      #pragma unroll
      for (int j = 0; j < 4; ++j) bf[j] = *(const bf16x8*)&Bs[(wn * 64 + j * 16) * 32 + fm];
      #pragma unroll
      for (int i = 0; i < 2; ++i)
        #pragma unroll
        for (int j = 0; j < 4; ++j)
          acc[i][j] = __builtin_amdgcn_mfma_f32_16x16x32_bf16(af[i], bf[j], acc[i][j], 0, 0, 0);
      __syncthreads();
    }
  }
  #pragma unroll
  for (int i = 0; i < 2; ++i) {
    int rbase = bm * 64 + wm * 32 + i * 16 + ((lane >> 4) << 2);
    #pragma unroll
    for (int j = 0; j < 4; ++j) {
      int col = bn * 128 + wn * 64 + j * 16 + (lane & 15);
      float bias = eb[col];
      #pragma unroll
      for (int r = 0; r < 4; ++r)
        enc[(size_t)(rbase + r) * PDIM + col] = acc[i][j][r] + bias;
    }
  }
}

// ---- normalize enc rows: fp32 copy + fp8 copy (scale 32) ---------------------
__global__ __launch_bounds__(256) void k_encnorm(const float* __restrict__ enc,
                                                 float* __restrict__ encn,
                                                 unsigned char* __restrict__ encf8) {
  int row = blockIdx.x * 4 + (threadIdx.x >> 6);
  int lane = threadIdx.x & 63;
  const float* p = enc + (size_t)row * PDIM + lane * 8;
  float4 v0 = *(const float4*)p;
  float4 v1 = *(const float4*)(p + 4);
  float s = v0.x*v0.x + v0.y*v0.y + v0.z*v0.z + v0.w*v0.w
          + v1.x*v1.x + v1.y*v1.y + v1.z*v1.z + v1.w*v1.w;
  #pragma unroll
  for (int m = 1; m < 64; m <<= 1) s += __shfl_xor(s, m);
  float rn = 1.0f / fmaxf(sqrtf(s), 1e-8f);
  float4 n0 = {v0.x*rn, v0.y*rn, v0.z*rn, v0.w*rn};
  float4 n1 = {v1.x*rn, v1.y*rn, v1.z*rn, v1.w*rn};
  float* q = encn + (size_t)row * PDIM + lane * 8;
  *(float4*)q = n0;
  *(float4*)(q + 4) = n1;
  uint2 o;
  o.x = f2f8(n0.x*32.f) | (f2f8(n0.y*32.f) << 8) | (f2f8(n0.z*32.f) << 16) | (f2f8(n0.w*32.f) << 24);
  o.y = f2f8(n1.x*32.f) | (f2f8(n1.y*32.f) << 8) | (f2f8(n1.z*32.f) << 16) | (f2f8(n1.w*32.f) << 24);
  *(uint2*)(encf8 + (size_t)row * PDIM + lane * 8) = o;
}

// ---- coarse sim: fp8 MFMA, A-resident-in-LDS, barrier-free, depth-4 prefetch -
__global__ __launch_bounds__(512, 4) void k_sim(const unsigned char* __restrict__ A,
                                                const unsigned char* __restrict__ B,
                                                int* __restrict__ cnt,
                                                float* __restrict__ cval,
                                                int* __restrict__ cidx) {
  __shared__ __align__(16) unsigned char As[65536];  // [16 kt][128 row][32 B]
  const int l = blockIdx.x;
  const int bn = 2 * (l & 7) + (l >> 8);   // XCD = l%8 -> bn in {2x, 2x+1}
  const int bm = (l >> 3) & 31;
  const int nb0 = bn * 4096;
  const int tid = threadIdx.x, lane = tid & 63, w = tid >> 6;

  {
    int row = (tid >> 1) & 127;
    int kt0 = tid >> 8;
    int c = (tid & 1) * 16;
    const unsigned char* g = A + (size_t)(bm * 128 + row) * PDIM + kt0 * 32 + c;
    #pragma unroll
    for (int s = 0; s < 8; ++s)
      gl2lds16(g + s * 64, &As[s * 8192 + tid * 16]);
  }

  f32x4 acc[8][2];
  #pragma unroll
  for (int m = 0; m < 8; ++m) {
    acc[m][0] = (f32x4){0.f, 0.f, 0.f, 0.f};
    acc[m][1] = (f32x4){0.f, 0.f, 0.f, 0.f};
  }
  const int baseA = (lane & 15) * 32 + (lane >> 4) * 8;
  const unsigned char* bp0 = B + (size_t)(nb0 + w * 32 + (lane & 15)) * PDIM + (lane >> 4) * 8;
  const unsigned char* bp1 = bp0 + 16 * PDIM;

  __syncthreads();   // A-tile ready; no barriers after this point

  long rq0[4], rq1[4];
  #pragma unroll
  for (int u = 0; u < 4; ++u) {
    rq0[u] = *(const long*)bp0;
    rq1[u] = *(const long*)bp1;
    bp0 += 32; bp1 += 32;
  }
  const float THRS = 112.64f;   // 0.11 * 32 * 32

  for (int it = 0; it < 256; ++it) {
    const int kt = it & 15;
    const int slot = it & 3;
    long bc0 = rq0[slot], bc1 = rq1[slot];
    int ip = it + 4;
    if (ip < 256) {
      rq0[slot] = *(const long*)bp0;
      rq1[slot] = *(const long*)bp1;
      long d = ((ip & 15) == 15) ? (long)(256 * PDIM - 15 * 32) : 32;
      bp0 += d; bp1 += d;
    }
    long a[8];
    #pragma unroll
    for (int m = 0; m < 8; ++m)
      a[m] = *(const long*)&As[kt * 4096 + m * 512 + baseA];
    #pragma unroll
    for (int m = 0; m < 8; ++m) {
      acc[m][0] = __builtin_amdgcn_mfma_f32_16x16x32_fp8_fp8(a[m], bc0, acc[m][0], 0, 0, 0);
      acc[m][1] = __builtin_amdgcn_mfma_f32_16x16x32_fp8_fp8(a[m], bc1, acc[m][1], 0, 0, 0);
    }
    if (kt == 15) {
      int ncol = nb0 + (it >> 4) * 256 + w * 32;
      #pragma unroll
      for (int m = 0; m < 8; ++m) {
        int tokbase = bm * 128 + m * 16 + ((lane >> 4) << 2);
        #pragma unroll
        for (int j = 0; j < 2; ++j) {
          int pc = ncol + j * 16 + (lane & 15);
          #pragma unroll
          for (int r = 0; r < 4; ++r) {
            float v = acc[m][j][r];
            if (v > THRS) {
              int tt = tokbase + r;
              int pos = atomicAdd(&cnt[tt], 1);
              if (pos < CAP) {
                cval[(size_t)tt * CAP + pos] = v;
                cidx[(size_t)tt * CAP + pos] = pc;
              }
            }
            acc[m][j][r] = 0.f;
          }
        }
      }
    }
  }
}

// ---- per-token select: histogram top-256 -> bf16 rerank -> sort256 ->
//      fp32 verify window (in-wave top16) -> winner-sum. No 1024-sort.
__global__ __launch_bounds__(256, 8) void k_select(const float* __restrict__ pat,
                                                   const float* __restrict__ prn,
                                                   const float* __restrict__ pnorm_,
                                                   const u16* __restrict__ pnb,
                                                   const float* __restrict__ encn,
                                                   const int* __restrict__ cnt,
                                                   const float* __restrict__ cval,
                                                   const int* __restrict__ cidx,
                                                   u16* __restrict__ meanb) {
  __shared__ __align__(16) u64 keys[CAP];   // stash; reused as wsum[4][512] later
  __shared__ int hist[256];                 // histogram -> suffix sums
  __shared__ int fidx[RSEL];
  __shared__ float fs[RSEL];
  __shared__ u64 keys2[RSEL];
  __shared__ float fverify[WIN];
  __shared__ int wl[128];
  __shared__ int sb[4];                     // bstar, t1, hiC, bC
  const int t = blockIdx.x;
  const int tid = threadIdx.x;
  const int lane = tid & 63;
  const int w = tid >> 6;
  const int n = min(cnt[t], CAP);
  const float THRS = 112.64f;

  // phase 1: stash candidates + histogram coarse vals (bin width 0.8)
  hist[tid] = 0;
  __syncthreads();
  for (int i = tid; i < n; i += 256) {
    float v = cval[(size_t)t * CAP + i];
    int id = cidx[(size_t)t * CAP + i];
    keys[i] = ((u64)fkey(v) << 32) | (u32)id;
    int bin = min((int)((v - THRS) * 1.25f), 255);
    atomicAdd(&hist[bin], 1);
  }
  __syncthreads();
  // phase 2: suffix sums hist[b] = #candidates with bin >= b
  for (int off = 1; off < 256; off <<= 1) {
    int add = (tid + off < 256) ? hist[tid + off] : 0;
    __syncthreads();
    hist[tid] += add;
    __syncthreads();
  }
  // find boundary bin bstar: take all bins > bstar (t1 entries), fill from bstar
  fidx[tid] = -1;
  if (tid == 0) {
    sb[2] = 0; sb[3] = 0;
    if (hist[0] <= RSEL) { sb[0] = -1; sb[1] = 0; }
  }
  if (hist[tid] > RSEL && (tid == 255 || hist[tid + 1] <= RSEL)) {
    sb[0] = tid;
    sb[1] = (tid == 255) ? 0 : hist[tid + 1];
  }
  __syncthreads();
  const int bstar = sb[0], t1 = sb[1];
  // phase 3: compact selected candidate indices into fidx[0..RSEL)
  for (int i = tid; i < n; i += 256) {
    u64 k = keys[i];
    float v = __uint_as_float((u32)(k >> 32) ^ 0x80000000u);  // all vals > 0
    int id = (int)(u32)(k & 0xFFFFFFFFull);
    int bin = min((int)((v - THRS) * 1.25f), 255);
    if (bin > bstar) {
      int pos = atomicAdd(&sb[2], 1);
      fidx[pos] = id;
    } else if (bin == bstar) {
      int pos = t1 + atomicAdd(&sb[3], 1);
      if (pos < RSEL) fidx[pos] = id;
    }
  }
  __syncthreads();

  const float* er = encn + (size_t)t * PDIM + lane * 8;
  float4 e0 = *(const float4*)er;
  float4 e1 = *(const float4*)(er + 4);

  // phase 4: bf16 rerank of the selected 256 (2-deep MLP, register-light)
  for (int c0 = w * 64; c0 < w * 64 + 64; c0 += 2) {
    int id[2]; bool ok[2]; uint4 q[2];
    #pragma unroll
    for (int u = 0; u < 2; ++u) {
      int iv = fidx[c0 + u];
      ok[u] = (iv >= 0);
      id[u] = ok[u] ? iv : 0;
      q[u] = *(const uint4*)(pnb + (size_t)id[u] * PDIM + lane * 8);
    }
    #pragma unroll
    for (int u = 0; u < 2; ++u) {
      float dd = b2f(q[u].x & 0xffffu)*e0.x + b2f(q[u].x >> 16)*e0.y
               + b2f(q[u].y & 0xffffu)*e0.z + b2f(q[u].y >> 16)*e0.w
               + b2f(q[u].z & 0xffffu)*e1.x + b2f(q[u].z >> 16)*e1.y
               + b2f(q[u].w & 0xffffu)*e1.z + b2f(q[u].w >> 16)*e1.w;
      #pragma unroll
      for (int m = 1; m < 64; m <<= 1) dd += __shfl_xor(dd, m);
      if (lane == 0) fs[c0 + u] = dd;
    }
  }
  __syncthreads();
  // phase 5: sort the 256 (desc val, asc idx via key encoding)
  {
    int iv = fidx[tid];
    keys2[tid] = (iv >= 0) ? (((u64)(~fkey(fs[tid])) << 32) | (u32)iv) : ~0ull;
  }
  __syncthreads();
  for (int k = 2; k <= 256; k <<= 1) {
    for (int j = k >> 1; j > 0; j >>= 1) {
      int ixj = tid ^ j;
      if (ixj > tid) {
        u64 a = keys2[tid], b = keys2[ixj];
        if ((a > b) == ((tid & k) == 0)) { keys2[tid] = b; keys2[ixj] = a; }
      }
      __syncthreads();
    }
  }
  // phase 6: fp32 verify of refined ranks [WLO, WLO+WIN)
  for (int b = 0; b < 2; ++b) {
    int c0 = WLO + w * 8 + b * 4;
    #pragma unroll
    for (int uu = 0; uu < 2; ++uu) {
      int c = c0 + uu * 2;
      int id[2]; bool ok[2]; float4 p0[2], p1[2];
      #pragma unroll
      for (int u = 0; u < 2; ++u) {
        int iv = (int)(u32)(keys2[c + u] & 0xFFFFFFFFull);
        ok[u] = ((u32)iv < (u32)NPAT);
        id[u] = ok[u] ? iv : 0;
        const float* pr = pat + (size_t)id[u] * PDIM + lane * 8;
        p0[u] = *(const float4*)pr;
        p1[u] = *(const float4*)(pr + 4);
      }
      #pragma unroll
      for (int u = 0; u < 2; ++u) {
        float dd = p0[u].x*e0.x + p0[u].y*e0.y + p0[u].z*e0.z + p0[u].w*e0.w
                 + p1[u].x*e1.x + p1[u].y*e1.y + p1[u].z*e1.z + p1[u].w*e1.w;
        #pragma unroll
        for (int m = 1; m < 64; m <<= 1) dd += __shfl_xor(dd, m);
        if (lane == 0)
          fverify[c + u - WLO] = ok[u] ? dd * prn[id[u]] : -1e30f;
      }
    }
  }
  // final list: ranks [0,WLO) + top-16 of verified window (in-wave sort, wave 0)
  if (tid < WLO) wl[tid] = (int)(u32)(keys2[tid] & 0xFFFFFFFFull);
  __syncthreads();
  if (w == 0) {
    u64 key = ~0ull;
    if (lane < WIN) {
      int iv = (int)(u32)(keys2[WLO + lane] & 0xFFFFFFFFull);
      key = ((u64)(~fkey(fverify[lane])) << 32) | (u32)iv;
    }
    #pragma unroll
    for (int k = 2; k <= 64; k <<= 1) {
      #pragma unroll
      for (int j = k >> 1; j > 0; j >>= 1) {
        u64 other = (u64)__shfl_xor((long long)key, j);
        bool up = ((lane & k) == 0);
        bool takeMin = (up == ((lane & j) == 0));
        bool less = key < other;
        key = (less == takeMin) ? key : other;
      }
    }
    if (lane < 128 - WLO) wl[WLO + lane] = (int)(u32)(key & 0xFFFFFFFFull);
  }
  __syncthreads();

  // phase 7: winner-sum (bf16 normalized rows x stored norm), wsum overlays keys
  float* wsumf = (float*)keys;   // [4][512]
  float4 s0 = {0,0,0,0}, s1 = {0,0,0,0};
  for (int c0 = w * 32; c0 < w * 32 + 32; c0 += 2) {
    int id[2]; float nm[2]; uint4 q[2];
    #pragma unroll
    for (int u = 0; u < 2; ++u) {
      int iv = wl[c0 + u];
      bool ok = ((u32)iv < (u32)NPAT);
      id[u] = ok ? iv : 0;
      q[u] = *(const uint4*)(pnb + (size_t)id[u] * PDIM + lane * 8);
      nm[u] = ok ? pnorm_[id[u]] : 0.0f;
    }
    #pragma unroll
    for (int u = 0; u < 2; ++u) {
      s0.x += b2f(q[u].x & 0xffffu) * nm[u]; s0.y += b2f(q[u].x >> 16) * nm[u];
      s0.z += b2f(q[u].y & 0xffffu) * nm[u]; s0.w += b2f(q[u].y >> 16) * nm[u];
      s1.x += b2f(q[u].z & 0xffffu) * nm[u]; s1.y += b2f(q[u].z >> 16) * nm[u];
      s1.z += b2f(q[u].w & 0xffffu) * nm[u]; s1.w += b2f(q[u].w >> 16) * nm[u];
    }
  }
  *(float4*)&wsumf[w * PDIM + lane * 8]     = s0;
  *(float4*)&wsumf[w * PDIM + lane * 8 + 4] = s1;
  __syncthreads();
  for (int dd = tid; dd < PDIM; dd += 256) {
    float m = (wsumf[dd] + wsumf[PDIM + dd] + wsumf[2 * PDIM + dd] + wsumf[3 * PDIM + dd])
              * (1.0f / 128.0f);
    meanb[(size_t)t * PDIM + dd] = f2b(m);
  }
}

// ---- decoder (bf16 MFMA): out = x + alpha*(mean @ dec_w^T + dec_b) -----------
__global__ __launch_bounds__(256) void k_dec(const u16* __restrict__ A,
                                             const u16* __restrict__ B,
                                             const float* __restrict__ x,
                                             const float* __restrict__ alpha,
                                             const float* __restrict__ db,
                                             float* __restrict__ out) {
  __shared__ __align__(16) u16 As[128 * 32];
  __shared__ __align__(16) u16 Bs[128 * 32];
  const int bm = blockIdx.x, bn = blockIdx.y;
  const int tid = threadIdx.x, lane = tid & 63, w = tid >> 6;
  const int wm = w >> 1, wn = w & 1;
  f32x4 acc[4][4];
  #pragma unroll
  for (int i = 0; i < 4; ++i)
    #pragma unroll
    for (int j = 0; j < 4; ++j) acc[i][j] = (f32x4){0.f, 0.f, 0.f, 0.f};

  const int c0 = w * 2, c1 = w * 2 + 1;
  const int lrow = lane >> 2, lk = (lane & 3) * 8;
  const u16* gA0 = A + (size_t)(bm * 128 + c0 * 16 + lrow) * PDIM + lk;
  const u16* gA1 = A + (size_t)(bm * 128 + c1 * 16 + lrow) * PDIM + lk;
  const u16* gB0 = B + (size_t)(bn * 128 + c0 * 16 + lrow) * PDIM + lk;
  const u16* gB1 = B + (size_t)(bn * 128 + c1 * 16 + lrow) * PDIM + lk;
  u16* lA0 = &As[c0 * 512]; u16* lA1 = &As[c1 * 512];
  u16* lB0 = &Bs[c0 * 512]; u16* lB1 = &Bs[c1 * 512];
  const int fm = (lane & 15) * 32 + (lane >> 4) * 8;

  for (int kt = 0; kt < 16; ++kt) {
    gl2lds16(gA0 + kt * 32, lA0);
    gl2lds16(gA1 + kt * 32, lA1);
    gl2lds16(gB0 + kt * 32, lB0);
    gl2lds16(gB1 + kt * 32, lB1);
    __syncthreads();
    bf16x8 af[4], bf[4];
    #pragma unroll
    for (int i = 0; i < 4; ++i) {
      af[i] = *(const bf16x8*)&As[(wm * 64 + i * 16) * 32 + fm];
      bf[i] = *(const bf16x8*)&Bs[(wn * 64 + i * 16) * 32 + fm];
    }
    #pragma unroll
    for (int i = 0; i < 4; ++i)
      #pragma unroll
      for (int j = 0; j < 4; ++j)
        acc[i][j] = __builtin_amdgcn_mfma_f32_16x16x32_bf16(af[i], bf[j], acc[i][j], 0, 0, 0);
    __syncthreads();
  }

  const float al = alpha[0];
  #pragma unroll
  for (int i = 0; i < 4; ++i) {
    int tbase = bm * 128 + wm * 64 + i * 16 + ((lane >> 4) << 2);
    #pragma unroll
    for (int j = 0; j < 4; ++j) {
      int dcol = bn * 128 + wn * 64 + j * 16 + (lane & 15);
      float bias = db[dcol];
      #pragma unroll
      for (int r = 0; r < 4; ++r) {
        int tt = tbase + r;
        size_t oi = (size_t)tt * DDIM + dcol;
        out[oi] = x[oi] + al * (acc[i][j][r] + bias);
      }
    }
  }
}

extern "C" void kernel_launch(void* const* d_in, const int* in_sizes, int n_in,
                              void* d_out, int out_size, void* d_ws, size_t ws_size,
                              hipStream_t stream) {
  const float* x     = (const float*)d_in[0];
  const float* pat   = (const float*)d_in[1];
  const float* alpha = (const float*)d_in[2];
  const float* enc_w = (const float*)d_in[3];
  const float* enc_b = (const float*)d_in[4];
  const float* dec_w = (const float*)d_in[5];
  const float* dec_b = (const float*)d_in[6];
  float* out = (float*)d_out;

  char* wsb = (char*)d_ws;
  size_t o = 0;
  auto alloc = [&](size_t bytes) -> void* {
    void* p = wsb + o;
    o += (bytes + 255) & ~(size_t)255;
    return p;
  };
  unsigned char* pnf8  = (unsigned char*)alloc((size_t)NPAT * PDIM);      // 32 MB
  u16*   pnb    = (u16*)  alloc((size_t)NPAT * PDIM * 2);                 // 64 MB
  float* prn    = (float*)alloc((size_t)NPAT * 4);                        // 256 KB
  float* pnorm_ = (float*)alloc((size_t)NPAT * 4);                        // 256 KB
  u16*   xh     = (u16*)  alloc((size_t)TOK * DDIM * 2);                  // 8 MB
  u16*   xl     = (u16*)  alloc((size_t)TOK * DDIM * 2);                  // 8 MB
  u16*   wh     = (u16*)  alloc((size_t)PDIM * DDIM * 2);                 // 1 MB
  u16*   wl_    = (u16*)  alloc((size_t)PDIM * DDIM * 2);                 // 1 MB
  float* enc    = (float*)alloc((size_t)TOK * PDIM * 4);                  // 8 MB
  float* encn   = (float*)alloc((size_t)TOK * PDIM * 4);                  // 8 MB
  unsigned char* encf8 = (unsigned char*)alloc((size_t)TOK * PDIM);       // 2 MB
  int*   ccnt   = (int*)  alloc((size_t)TOK * 4);                         // 16 KB
  float* cvals  = (float*)alloc((size_t)TOK * CAP * 4);                   // 16 MB
  int*   cids   = (int*)  alloc((size_t)TOK * CAP * 4);                   // 16 MB
  u16*   meanb  = (u16*)  alloc((size_t)TOK * PDIM * 2);                  // 4 MB
  u16*   decwb  = (u16*)  alloc((size_t)DDIM * PDIM * 2);                 // 1 MB
  (void)ws_size; (void)in_sizes; (void)n_in; (void)out_size;

  k_patnorm<<<dim3(NPAT / 4), dim3(256), 0, stream>>>(pat, pnf8, pnb, prn, pnorm_);
  k_zero<<<dim3(TOK / 256), dim3(256), 0, stream>>>(ccnt, TOK);
  k_tobf16<<<dim3((DDIM * PDIM) / 256), dim3(256), 0, stream>>>(dec_w, decwb, DDIM * PDIM);
  k_split4<<<dim3((TOK * DDIM / 4) / 256), dim3(256), 0, stream>>>(x, xh, xl, TOK * DDIM / 4);
  k_split4<<<dim3((PDIM * DDIM / 4) / 256), dim3(256), 0, stream>>>(enc_w, wh, wl_, PDIM * DDIM / 4);
  k_enc3<<<dim3(TOK / 64, PDIM / 128), dim3(256), 0, stream>>>(xh, xl, wh, wl_, enc_b, enc);
  k_encnorm<<<dim3(TOK / 4), dim3(256), 0, stream>>>(enc, encn, encf8);
  k_sim<<<dim3(512), dim3(512), 0, stream>>>(encf8, pnf8, ccnt, cvals, cids);
  k_select<<<dim3(TOK), dim3(256), 0, stream>>>(pat, prn, pnorm_, pnb, encn, ccnt, cvals, cids, meanb);
  k_dec<<<dim3(TOK / 128, DDIM / 128), dim3(256), 0, stream>>>(meanb, decwb, x, alpha, dec_b, out);
}

// Round 5
// 1088.862 us; speedup vs baseline: 1.1959x; 1.1211x over previous
//
#include <hip/hip_runtime.h>
#include <hip/hip_fp8.h>

#define TOK 4096
#define NPAT 65536
#define PDIM 512
#define DDIM 1024
#define CAP 1024
#define RSEL 256
#define WLO 112   // fp32-verify window: refined ranks [WLO, WLO+WIN)
#define WIN 32

typedef __attribute__((ext_vector_type(8))) short bf16x8;
typedef __attribute__((ext_vector_type(4))) float f32x4;
typedef unsigned short u16;
typedef unsigned int u32;
typedef unsigned long long u64;

__device__ __forceinline__ u16 f2b(float f) {
  union { float f; u32 u; } x; x.f = f;
  u32 r = x.u + 0x7FFFu + ((x.u >> 16) & 1u);   // RNE fp32->bf16
  return (u16)(r >> 16);
}
__device__ __forceinline__ float b2f(u32 h) {
  union { u32 u; float f; } x; x.u = h << 16; return x.f;
}
__device__ __forceinline__ u32 f2f8(float v) {   // OCP e4m3, RNE+sat via HW
  __hip_fp8_e4m3 t(v);
  return (u32)(unsigned char)t.__x;
}

__device__ __forceinline__ void gl2lds16(const void* g, void* l) {
  __builtin_amdgcn_global_load_lds((const __attribute__((address_space(1))) u32*)g,
                                   (__attribute__((address_space(3))) u32*)l, 16, 0, 0);
}

__device__ __forceinline__ u32 fkey(float f) {  // monotonic float->uint
  u32 u = __float_as_uint(f);
  u ^= (u >> 31) ? 0xFFFFFFFFu : 0x80000000u;
  return u;
}

// ---- pattern norms + normalized fp8 (scale 32) + normalized bf16 copies ------
__global__ __launch_bounds__(256) void k_patnorm(const float* __restrict__ pat,
                                                 unsigned char* __restrict__ pnf8,
                                                 u16* __restrict__ pnb,
                                                 float* __restrict__ prn,
                                                 float* __restrict__ pnorm_) {
  int row = blockIdx.x * 4 + (threadIdx.x >> 6);
  int lane = threadIdx.x & 63;
  const float* p = pat + (size_t)row * PDIM + lane * 8;
  float4 v0 = *(const float4*)p;
  float4 v1 = *(const float4*)(p + 4);
  float s = v0.x*v0.x + v0.y*v0.y + v0.z*v0.z + v0.w*v0.w
          + v1.x*v1.x + v1.y*v1.y + v1.z*v1.z + v1.w*v1.w;
  #pragma unroll
  for (int m = 1; m < 64; m <<= 1) s += __shfl_xor(s, m);
  float nrm = fmaxf(sqrtf(s), 1e-8f);
  float rn = 1.0f / nrm;
  if (lane == 0) { prn[row] = rn; pnorm_[row] = nrm; }
  float sc = rn * 32.0f;
  uint2 o;
  o.x = f2f8(v0.x*sc) | (f2f8(v0.y*sc) << 8) | (f2f8(v0.z*sc) << 16) | (f2f8(v0.w*sc) << 24);
  o.y = f2f8(v1.x*sc) | (f2f8(v1.y*sc) << 8) | (f2f8(v1.z*sc) << 16) | (f2f8(v1.w*sc) << 24);
  *(uint2*)(pnf8 + (size_t)row * PDIM + lane * 8) = o;
  uint4 ob;
  ob.x = (u32)f2b(v0.x*rn) | ((u32)f2b(v0.y*rn) << 16);
  ob.y = (u32)f2b(v0.z*rn) | ((u32)f2b(v0.w*rn) << 16);
  ob.z = (u32)f2b(v1.x*rn) | ((u32)f2b(v1.y*rn) << 16);
  ob.w = (u32)f2b(v1.z*rn) | ((u32)f2b(v1.w*rn) << 16);
  *(uint4*)(pnb + (size_t)row * PDIM + lane * 8) = ob;
}

__global__ __launch_bounds__(256) void k_zero(int* __restrict__ p, int n) {
  int i = blockIdx.x * 256 + threadIdx.x;
  if (i < n) p[i] = 0;
}

__global__ __launch_bounds__(256) void k_tobf16(const float* __restrict__ s,
                                                u16* __restrict__ d, int n) {
  int i = blockIdx.x * 256 + threadIdx.x;
  if (i < n) d[i] = f2b(s[i]);
}

// ---- split fp32 -> bf16 hi/lo (float4 per thread) ----------------------------
__global__ __launch_bounds__(256) void k_split4(const float* __restrict__ s,
                                                u16* __restrict__ hi,
                                                u16* __restrict__ lo, int n4) {
  int i = blockIdx.x * 256 + threadIdx.x;
  if (i >= n4) return;
  float4 v = *(const float4*)(s + (size_t)i * 4);
  ushort4 h, l;
  h.x = f2b(v.x); l.x = f2b(v.x - b2f((u32)h.x));
  h.y = f2b(v.y); l.y = f2b(v.y - b2f((u32)h.y));
  h.z = f2b(v.z); l.z = f2b(v.z - b2f((u32)h.z));
  h.w = f2b(v.w); l.w = f2b(v.w - b2f((u32)h.w));
  *(ushort4*)(hi + (size_t)i * 4) = h;
  *(ushort4*)(lo + (size_t)i * 4) = l;
}

// ---- encoder via split-bf16 MFMA: enc = xh(wh+wl)^T + xl wh^T + eb -----------
__global__ __launch_bounds__(256) void k_enc3(const u16* __restrict__ xh,
                                              const u16* __restrict__ xl,
                                              const u16* __restrict__ wh,
                                              const u16* __restrict__ wl,
                                              const float* __restrict__ eb,
                                              float* __restrict__ enc) {
  __shared__ __align__(16) u16 As[64 * 32];
  __shared__ __align__(16) u16 Bs[128 * 32];
  const int bm = blockIdx.x, bn = blockIdx.y;
  const int tid = threadIdx.x, lane = tid & 63, w = tid >> 6;
  const int wm = w >> 1, wn = w & 1;
  f32x4 acc[2][4];
  #pragma unroll
  for (int i = 0; i < 2; ++i)
    #pragma unroll
    for (int j = 0; j < 4; ++j) acc[i][j] = (f32x4){0.f, 0.f, 0.f, 0.f};

  const int arow = tid >> 2, ael = (tid & 3) * 8;
  const int fm = (lane & 15) * 32 + (lane >> 4) * 8;
  const u16* APh[3] = {xh, xh, xl};
  const u16* BPh[3] = {wh, wl, wh};

  for (int ph = 0; ph < 3; ++ph) {
    const u16* Ag = APh[ph] + (size_t)(bm * 64 + arow) * DDIM + ael;
    const u16* Bg0 = BPh[ph] + (size_t)(bn * 128 + arow) * DDIM + ael;
    const u16* Bg1 = BPh[ph] + (size_t)(bn * 128 + 64 + arow) * DDIM + ael;
    for (int kt = 0; kt < 32; ++kt) {
      gl2lds16(Ag + kt * 32, As + (size_t)tid * 8);
      gl2lds16(Bg0 + kt * 32, Bs + (size_t)tid * 8);
      gl2lds16(Bg1 + kt * 32, Bs + (size_t)(tid + 256) * 8);
      __syncthreads();
      bf16x8 af[2], bf[4];
      #pragma unroll
      for (int i = 0; i < 2; ++i) af[i] = *(const bf16x8*)&As[(wm * 32 + i * 16) * 32 + fm];
      #pragma unroll
      for (int j = 0; j < 4; ++j) bf[j] = *(const bf16x8*)&Bs[(wn * 64 + j * 16) * 32 + fm];
      #pragma unroll
      for (int i = 0; i < 2; ++i)
        #pragma unroll
        for (int j = 0; j < 4; ++j)
          acc[i][j] = __builtin_amdgcn_mfma_f32_16x16x32_bf16(af[i], bf[j], acc[i][j], 0, 0, 0);
      __syncthreads();
    }
  }
  #pragma unroll
  for (int i = 0; i < 2; ++i) {
    int rbase = bm * 64 + wm * 32 + i * 16 + ((lane >> 4) << 2);
    #pragma unroll
    for (int j = 0; j < 4; ++j) {
      int col = bn * 128 + wn * 64 + j * 16 + (lane & 15);
      float bias = eb[col];
      #pragma unroll
      for (int r = 0; r < 4; ++r)
        enc[(size_t)(rbase + r) * PDIM + col] = acc[i][j][r] + bias;
    }
  }
}

// ---- normalize enc rows: fp32 copy + fp8 copy (scale 32) ---------------------
__global__ __launch_bounds__(256) void k_encnorm(const float* __restrict__ enc,
                                                 float* __restrict__ encn,
                                                 unsigned char* __restrict__ encf8) {
  int row = blockIdx.x * 4 + (threadIdx.x >> 6);
  int lane = threadIdx.x & 63;
  const float* p = enc + (size_t)row * PDIM + lane * 8;
  float4 v0 = *(const float4*)p;
  float4 v1 = *(const float4*)(p + 4);
  float s = v0.x*v0.x + v0.y*v0.y + v0.z*v0.z + v0.w*v0.w
          + v1.x*v1.x + v1.y*v1.y + v1.z*v1.z + v1.w*v1.w;
  #pragma unroll
  for (int m = 1; m < 64; m <<= 1) s += __shfl_xor(s, m);
  float rn = 1.0f / fmaxf(sqrtf(s), 1e-8f);
  float4 n0 = {v0.x*rn, v0.y*rn, v0.z*rn, v0.w*rn};
  float4 n1 = {v1.x*rn, v1.y*rn, v1.z*rn, v1.w*rn};
  float* q = encn + (size_t)row * PDIM + lane * 8;
  *(float4*)q = n0;
  *(float4*)(q + 4) = n1;
  uint2 o;
  o.x = f2f8(n0.x*32.f) | (f2f8(n0.y*32.f) << 8) | (f2f8(n0.z*32.f) << 16) | (f2f8(n0.w*32.f) << 24);
  o.y = f2f8(n1.x*32.f) | (f2f8(n1.y*32.f) << 8) | (f2f8(n1.z*32.f) << 16) | (f2f8(n1.w*32.f) << 24);
  *(uint2*)(encf8 + (size_t)row * PDIM + lane * 8) = o;
}

// ---- coarse sim: fp8 MFMA, A-resident-in-LDS, barrier-free, depth-4 prefetch -
__global__ __launch_bounds__(512, 4) void k_sim(const unsigned char* __restrict__ A,
                                                const unsigned char* __restrict__ B,
                                                int* __restrict__ cnt,
                                                float* __restrict__ cval,
                                                int* __restrict__ cidx) {
  __shared__ __align__(16) unsigned char As[65536];  // [16 kt][128 row][32 B]
  const int l = blockIdx.x;
  const int bn = 2 * (l & 7) + (l >> 8);   // XCD = l%8 -> bn in {2x, 2x+1}
  const int bm = (l >> 3) & 31;
  const int nb0 = bn * 4096;
  const int tid = threadIdx.x, lane = tid & 63, w = tid >> 6;

  {
    int row = (tid >> 1) & 127;
    int kt0 = tid >> 8;
    int c = (tid & 1) * 16;
    const unsigned char* g = A + (size_t)(bm * 128 + row) * PDIM + kt0 * 32 + c;
    #pragma unroll
    for (int s = 0; s < 8; ++s)
      gl2lds16(g + s * 64, &As[s * 8192 + tid * 16]);
  }

  f32x4 acc[8][2];
  #pragma unroll
  for (int m = 0; m < 8; ++m) {
    acc[m][0] = (f32x4){0.f, 0.f, 0.f, 0.f};
    acc[m][1] = (f32x4){0.f, 0.f, 0.f, 0.f};
  }
  const int baseA = (lane & 15) * 32 + (lane >> 4) * 8;
  const unsigned char* bp0 = B + (size_t)(nb0 + w * 32 + (lane & 15)) * PDIM + (lane >> 4) * 8;
  const unsigned char* bp1 = bp0 + 16 * PDIM;

  __syncthreads();   // A-tile ready; no barriers after this point

  long rq0[4], rq1[4];
  #pragma unroll
  for (int u = 0; u < 4; ++u) {
    rq0[u] = *(const long*)bp0;
    rq1[u] = *(const long*)bp1;
    bp0 += 32; bp1 += 32;
  }
  const float THRS = 112.64f;   // 0.11 * 32 * 32

  for (int it = 0; it < 256; ++it) {
    const int kt = it & 15;
    const int slot = it & 3;
    long bc0 = rq0[slot], bc1 = rq1[slot];
    int ip = it + 4;
    if (ip < 256) {
      rq0[slot] = *(const long*)bp0;
      rq1[slot] = *(const long*)bp1;
      long d = ((ip & 15) == 15) ? (long)(256 * PDIM - 15 * 32) : 32;
      bp0 += d; bp1 += d;
    }
    long a[8];
    #pragma unroll
    for (int m = 0; m < 8; ++m)
      a[m] = *(const long*)&As[kt * 4096 + m * 512 + baseA];
    #pragma unroll
    for (int m = 0; m < 8; ++m) {
      acc[m][0] = __builtin_amdgcn_mfma_f32_16x16x32_fp8_fp8(a[m], bc0, acc[m][0], 0, 0, 0);
      acc[m][1] = __builtin_amdgcn_mfma_f32_16x16x32_fp8_fp8(a[m], bc1, acc[m][1], 0, 0, 0);
    }
    if (kt == 15) {
      int ncol = nb0 + (it >> 4) * 256 + w * 32;
      #pragma unroll
      for (int m = 0; m < 8; ++m) {
        int tokbase = bm * 128 + m * 16 + ((lane >> 4) << 2);
        #pragma unroll
        for (int j = 0; j < 2; ++j) {
          int pc = ncol + j * 16 + (lane & 15);
          #pragma unroll
          for (int r = 0; r < 4; ++r) {
            float v = acc[m][j][r];
            if (v > THRS) {
              int tt = tokbase + r;
              int pos = atomicAdd(&cnt[tt], 1);
              if (pos < CAP) {
                cval[(size_t)tt * CAP + pos] = v;
                cidx[(size_t)tt * CAP + pos] = pc;
              }
            }
            acc[m][j][r] = 0.f;
          }
        }
      }
    }
  }
}

// ---- per-token select: histogram top-256 -> bf16 rerank -> sort256 ->
//      fp32 verify window (in-wave top16) -> winner-sum.
// __launch_bounds__(256,4): 128-VGPR cap -> no scratch spills (R4: (256,8)
// clamped to 32 VGPR and spilled 1.3 GB of scratch traffic).
__global__ __launch_bounds__(256, 4) void k_select(const float* __restrict__ pat,
                                                   const float* __restrict__ prn,
                                                   const float* __restrict__ pnorm_,
                                                   const u16* __restrict__ pnb,
                                                   const float* __restrict__ encn,
                                                   const int* __restrict__ cnt,
                                                   const float* __restrict__ cval,
                                                   const int* __restrict__ cidx,
                                                   u16* __restrict__ meanb) {
  __shared__ __align__(16) u64 keys[CAP];   // stash; reused as wsum[4][512] later
  __shared__ int hist[256];                 // histogram -> suffix sums
  __shared__ int fidx[RSEL];
  __shared__ float fs[RSEL];
  __shared__ u64 keys2[RSEL];
  __shared__ float fverify[WIN];
  __shared__ int wl[128];
  __shared__ int sb[4];                     // bstar, t1, hiC, bC
  const int t = blockIdx.x;
  const int tid = threadIdx.x;
  const int lane = tid & 63;
  const int w = tid >> 6;
  const int n = min(cnt[t], CAP);
  const float THRS = 112.64f;

  // phase 1: stash candidates + histogram coarse vals (bin width 0.8)
  hist[tid] = 0;
  __syncthreads();
  for (int i = tid; i < n; i += 256) {
    float v = cval[(size_t)t * CAP + i];
    int id = cidx[(size_t)t * CAP + i];
    keys[i] = ((u64)fkey(v) << 32) | (u32)id;
    int bin = min((int)((v - THRS) * 1.25f), 255);
    atomicAdd(&hist[bin], 1);
  }
  __syncthreads();
  // phase 2: suffix sums hist[b] = #candidates with bin >= b
  for (int off = 1; off < 256; off <<= 1) {
    int add = (tid + off < 256) ? hist[tid + off] : 0;
    __syncthreads();
    hist[tid] += add;
    __syncthreads();
  }
  // find boundary bin bstar: take all bins > bstar (t1 entries), fill from bstar
  fidx[tid] = -1;
  if (tid == 0) {
    sb[2] = 0; sb[3] = 0;
    if (hist[0] <= RSEL) { sb[0] = -1; sb[1] = 0; }
  }
  if (hist[tid] > RSEL && (tid == 255 || hist[tid + 1] <= RSEL)) {
    sb[0] = tid;
    sb[1] = (tid == 255) ? 0 : hist[tid + 1];
  }
  __syncthreads();
  const int bstar = sb[0], t1 = sb[1];
  // phase 3: compact selected candidate indices into fidx[0..RSEL)
  for (int i = tid; i < n; i += 256) {
    u64 k = keys[i];
    float v = __uint_as_float((u32)(k >> 32) ^ 0x80000000u);  // all vals > 0
    int id = (int)(u32)(k & 0xFFFFFFFFull);
    int bin = min((int)((v - THRS) * 1.25f), 255);
    if (bin > bstar) {
      int pos = atomicAdd(&sb[2], 1);
      fidx[pos] = id;
    } else if (bin == bstar) {
      int pos = t1 + atomicAdd(&sb[3], 1);
      if (pos < RSEL) fidx[pos] = id;
    }
  }
  __syncthreads();

  const float* er = encn + (size_t)t * PDIM + lane * 8;
  float4 e0 = *(const float4*)er;
  float4 e1 = *(const float4*)(er + 4);

  // phase 4: bf16 rerank of the selected 256 (2-deep MLP)
  for (int c0 = w * 64; c0 < w * 64 + 64; c0 += 2) {
    int id[2]; bool ok[2]; uint4 q[2];
    #pragma unroll
    for (int u = 0; u < 2; ++u) {
      int iv = fidx[c0 + u];
      ok[u] = (iv >= 0);
      id[u] = ok[u] ? iv : 0;
      q[u] = *(const uint4*)(pnb + (size_t)id[u] * PDIM + lane * 8);
    }
    #pragma unroll
    for (int u = 0; u < 2; ++u) {
      float dd = b2f(q[u].x & 0xffffu)*e0.x + b2f(q[u].x >> 16)*e0.y
               + b2f(q[u].y & 0xffffu)*e0.z + b2f(q[u].y >> 16)*e0.w
               + b2f(q[u].z & 0xffffu)*e1.x + b2f(q[u].z >> 16)*e1.y
               + b2f(q[u].w & 0xffffu)*e1.z + b2f(q[u].w >> 16)*e1.w;
      #pragma unroll
      for (int m = 1; m < 64; m <<= 1) dd += __shfl_xor(dd, m);
      if (lane == 0) fs[c0 + u] = dd;
    }
  }
  __syncthreads();
  // phase 5: sort the 256 (desc val, asc idx via key encoding)
  {
    int iv = fidx[tid];
    keys2[tid] = (iv >= 0) ? (((u64)(~fkey(fs[tid])) << 32) | (u32)iv) : ~0ull;
  }
  __syncthreads();
  for (int k = 2; k <= 256; k <<= 1) {
    for (int j = k >> 1; j > 0; j >>= 1) {
      int ixj = tid ^ j;
      if (ixj > tid) {
        u64 a = keys2[tid], b = keys2[ixj];
        if ((a > b) == ((tid & k) == 0)) { keys2[tid] = b; keys2[ixj] = a; }
      }
      __syncthreads();
    }
  }
  // phase 6: fp32 verify of refined ranks [WLO, WLO+WIN)
  for (int b = 0; b < 2; ++b) {
    int c0 = WLO + w * 8 + b * 4;
    #pragma unroll
    for (int uu = 0; uu < 2; ++uu) {
      int c = c0 + uu * 2;
      int id[2]; bool ok[2]; float4 p0[2], p1[2];
      #pragma unroll
      for (int u = 0; u < 2; ++u) {
        int iv = (int)(u32)(keys2[c + u] & 0xFFFFFFFFull);
        ok[u] = ((u32)iv < (u32)NPAT);
        id[u] = ok[u] ? iv : 0;
        const float* pr = pat + (size_t)id[u] * PDIM + lane * 8;
        p0[u] = *(const float4*)pr;
        p1[u] = *(const float4*)(pr + 4);
      }
      #pragma unroll
      for (int u = 0; u < 2; ++u) {
        float dd = p0[u].x*e0.x + p0[u].y*e0.y + p0[u].z*e0.z + p0[u].w*e0.w
                 + p1[u].x*e1.x + p1[u].y*e1.y + p1[u].z*e1.z + p1[u].w*e1.w;
        #pragma unroll
        for (int m = 1; m < 64; m <<= 1) dd += __shfl_xor(dd, m);
        if (lane == 0)
          fverify[c + u - WLO] = ok[u] ? dd * prn[id[u]] : -1e30f;
      }
    }
  }
  // final list: ranks [0,WLO) + top-16 of verified window (in-wave sort, wave 0)
  if (tid < WLO) wl[tid] = (int)(u32)(keys2[tid] & 0xFFFFFFFFull);
  __syncthreads();
  if (w == 0) {
    u64 key = ~0ull;
    if (lane < WIN) {
      int iv = (int)(u32)(keys2[WLO + lane] & 0xFFFFFFFFull);
      key = ((u64)(~fkey(fverify[lane])) << 32) | (u32)iv;
    }
    #pragma unroll
    for (int k = 2; k <= 64; k <<= 1) {
      #pragma unroll
      for (int j = k >> 1; j > 0; j >>= 1) {
        u64 other = (u64)__shfl_xor((long long)key, j);
        bool up = ((lane & k) == 0);
        bool takeMin = (up == ((lane & j) == 0));
        bool less = key < other;
        key = (less == takeMin) ? key : other;
      }
    }
    if (lane < 128 - WLO) wl[WLO + lane] = (int)(u32)(key & 0xFFFFFFFFull);
  }
  __syncthreads();

  // phase 7: winner-sum (bf16 normalized rows x stored norm), wsum overlays keys
  float* wsumf = (float*)keys;   // [4][512]
  float4 s0 = {0,0,0,0}, s1 = {0,0,0,0};
  for (int c0 = w * 32; c0 < w * 32 + 32; c0 += 2) {
    int id[2]; float nm[2]; uint4 q[2];
    #pragma unroll
    for (int u = 0; u < 2; ++u) {
      int iv = wl[c0 + u];
      bool ok = ((u32)iv < (u32)NPAT);
      id[u] = ok ? iv : 0;
      q[u] = *(const uint4*)(pnb + (size_t)id[u] * PDIM + lane * 8);
      nm[u] = ok ? pnorm_[id[u]] : 0.0f;
    }
    #pragma unroll
    for (int u = 0; u < 2; ++u) {
      s0.x += b2f(q[u].x & 0xffffu) * nm[u]; s0.y += b2f(q[u].x >> 16) * nm[u];
      s0.z += b2f(q[u].y & 0xffffu) * nm[u]; s0.w += b2f(q[u].y >> 16) * nm[u];
      s1.x += b2f(q[u].z & 0xffffu) * nm[u]; s1.y += b2f(q[u].z >> 16) * nm[u];
      s1.z += b2f(q[u].w & 0xffffu) * nm[u]; s1.w += b2f(q[u].w >> 16) * nm[u];
    }
  }
  *(float4*)&wsumf[w * PDIM + lane * 8]     = s0;
  *(float4*)&wsumf[w * PDIM + lane * 8 + 4] = s1;
  __syncthreads();
  for (int dd = tid; dd < PDIM; dd += 256) {
    float m = (wsumf[dd] + wsumf[PDIM + dd] + wsumf[2 * PDIM + dd] + wsumf[3 * PDIM + dd])
              * (1.0f / 128.0f);
    meanb[(size_t)t * PDIM + dd] = f2b(m);
  }
}

// ---- decoder (bf16 MFMA): out = x + alpha*(mean @ dec_w^T + dec_b) -----------
__global__ __launch_bounds__(256) void k_dec(const u16* __restrict__ A,
                                             const u16* __restrict__ B,
                                             const float* __restrict__ x,
                                             const float* __restrict__ alpha,
                                             const float* __restrict__ db,
                                             float* __restrict__ out) {
  __shared__ __align__(16) u16 As[128 * 32];
  __shared__ __align__(16) u16 Bs[128 * 32];
  const int bm = blockIdx.x, bn = blockIdx.y;
  const int tid = threadIdx.x, lane = tid & 63, w = tid >> 6;
  const int wm = w >> 1, wn = w & 1;
  f32x4 acc[4][4];
  #pragma unroll
  for (int i = 0; i < 4; ++i)
    #pragma unroll
    for (int j = 0; j < 4; ++j) acc[i][j] = (f32x4){0.f, 0.f, 0.f, 0.f};

  const int c0 = w * 2, c1 = w * 2 + 1;
  const int lrow = lane >> 2, lk = (lane & 3) * 8;
  const u16* gA0 = A + (size_t)(bm * 128 + c0 * 16 + lrow) * PDIM + lk;
  const u16* gA1 = A + (size_t)(bm * 128 + c1 * 16 + lrow) * PDIM + lk;
  const u16* gB0 = B + (size_t)(bn * 128 + c0 * 16 + lrow) * PDIM + lk;
  const u16* gB1 = B + (size_t)(bn * 128 + c1 * 16 + lrow) * PDIM + lk;
  u16* lA0 = &As[c0 * 512]; u16* lA1 = &As[c1 * 512];
  u16* lB0 = &Bs[c0 * 512]; u16* lB1 = &Bs[c1 * 512];
  const int fm = (lane & 15) * 32 + (lane >> 4) * 8;

  for (int kt = 0; kt < 16; ++kt) {
    gl2lds16(gA0 + kt * 32, lA0);
    gl2lds16(gA1 + kt * 32, lA1);
    gl2lds16(gB0 + kt * 32, lB0);
    gl2lds16(gB1 + kt * 32, lB1);
    __syncthreads();
    bf16x8 af[4], bf[4];
    #pragma unroll
    for (int i = 0; i < 4; ++i) {
      af[i] = *(const bf16x8*)&As[(wm * 64 + i * 16) * 32 + fm];
      bf[i] = *(const bf16x8*)&Bs[(wn * 64 + i * 16) * 32 + fm];
    }
    #pragma unroll
    for (int i = 0; i < 4; ++i)
      #pragma unroll
      for (int j = 0; j < 4; ++j)
        acc[i][j] = __builtin_amdgcn_mfma_f32_16x16x32_bf16(af[i], bf[j], acc[i][j], 0, 0, 0);
    __syncthreads();
  }

  const float al = alpha[0];
  #pragma unroll
  for (int i = 0; i < 4; ++i) {
    int tbase = bm * 128 + wm * 64 + i * 16 + ((lane >> 4) << 2);
    #pragma unroll
    for (int j = 0; j < 4; ++j) {
      int dcol = bn * 128 + wn * 64 + j * 16 + (lane & 15);
      float bias = db[dcol];
      #pragma unroll
      for (int r = 0; r < 4; ++r) {
        int tt = tbase + r;
        size_t oi = (size_t)tt * DDIM + dcol;
        out[oi] = x[oi] + al * (acc[i][j][r] + bias);
      }
    }
  }
}

extern "C" void kernel_launch(void* const* d_in, const int* in_sizes, int n_in,
                              void* d_out, int out_size, void* d_ws, size_t ws_size,
                              hipStream_t stream) {
  const float* x     = (const float*)d_in[0];
  const float* pat   = (const float*)d_in[1];
  const float* alpha = (const float*)d_in[2];
  const float* enc_w = (const float*)d_in[3];
  const float* enc_b = (const float*)d_in[4];
  const float* dec_w = (const float*)d_in[5];
  const float* dec_b = (const float*)d_in[6];
  float* out = (float*)d_out;

  char* wsb = (char*)d_ws;
  size_t o = 0;
  auto alloc = [&](size_t bytes) -> void* {
    void* p = wsb + o;
    o += (bytes + 255) & ~(size_t)255;
    return p;
  };
  unsigned char* pnf8  = (unsigned char*)alloc((size_t)NPAT * PDIM);      // 32 MB
  u16*   pnb    = (u16*)  alloc((size_t)NPAT * PDIM * 2);                 // 64 MB
  float* prn    = (float*)alloc((size_t)NPAT * 4);                        // 256 KB
  float* pnorm_ = (float*)alloc((size_t)NPAT * 4);                        // 256 KB
  u16*   xh     = (u16*)  alloc((size_t)TOK * DDIM * 2);                  // 8 MB
  u16*   xl     = (u16*)  alloc((size_t)TOK * DDIM * 2);                  // 8 MB
  u16*   wh     = (u16*)  alloc((size_t)PDIM * DDIM * 2);                 // 1 MB
  u16*   wl_    = (u16*)  alloc((size_t)PDIM * DDIM * 2);                 // 1 MB
  float* enc    = (float*)alloc((size_t)TOK * PDIM * 4);                  // 8 MB
  float* encn   = (float*)alloc((size_t)TOK * PDIM * 4);                  // 8 MB
  unsigned char* encf8 = (unsigned char*)alloc((size_t)TOK * PDIM);       // 2 MB
  int*   ccnt   = (int*)  alloc((size_t)TOK * 4);                         // 16 KB
  float* cvals  = (float*)alloc((size_t)TOK * CAP * 4);                   // 16 MB
  int*   cids   = (int*)  alloc((size_t)TOK * CAP * 4);                   // 16 MB
  u16*   meanb  = (u16*)  alloc((size_t)TOK * PDIM * 2);                  // 4 MB
  u16*   decwb  = (u16*)  alloc((size_t)DDIM * PDIM * 2);                 // 1 MB
  (void)ws_size; (void)in_sizes; (void)n_in; (void)out_size;

  k_patnorm<<<dim3(NPAT / 4), dim3(256), 0, stream>>>(pat, pnf8, pnb, prn, pnorm_);
  k_zero<<<dim3(TOK / 256), dim3(256), 0, stream>>>(ccnt, TOK);
  k_tobf16<<<dim3((DDIM * PDIM) / 256), dim3(256), 0, stream>>>(dec_w, decwb, DDIM * PDIM);
  k_split4<<<dim3((TOK * DDIM / 4) / 256), dim3(256), 0, stream>>>(x, xh, xl, TOK * DDIM / 4);
  k_split4<<<dim3((PDIM * DDIM / 4) / 256), dim3(256), 0, stream>>>(enc_w, wh, wl_, PDIM * DDIM / 4);
  k_enc3<<<dim3(TOK / 64, PDIM / 128), dim3(256), 0, stream>>>(xh, xl, wh, wl_, enc_b, enc);
  k_encnorm<<<dim3(TOK / 4), dim3(256), 0, stream>>>(enc, encn, encf8);
  k_sim<<<dim3(512), dim3(512), 0, stream>>>(encf8, pnf8, ccnt, cvals, cids);
  k_select<<<dim3(TOK), dim3(256), 0, stream>>>(pat, prn, pnorm_, pnb, encn, ccnt, cvals, cids, meanb);
  k_dec<<<dim3(TOK / 128, DDIM / 128), dim3(256), 0, stream>>>(meanb, decwb, x, alpha, dec_b, out);
}